// Round 3
// baseline (718.791 us; speedup 1.0000x reference)
//
#include <hip/hip_runtime.h>

// Correlation layer: out[b, dy*9+dx, y, x] =
//   (1/256) * sum_c frn[b,c,y,x] * fqn_pad[b,c,y+dy,x+dx]   (pad r=4)
// Identity: dot(frn,fqn) = dot(fr,fq) * invnorm(fr) * invnorm(fq).
//
// R3: wave-private blocks (64 thr), NO __syncthreads anywhere.
// - One wave owns a 64x4 tile for one dy; fq halo staged in its private
//   4.6KB LDS region; same-wave LDS in-order => no barriers.
// - fq staged one chunk (4 ch) ahead via register prefetch; fr rolled
//   one chunk ahead inside the compute loop.
// - fq norms: each lane accumulates sq of its own 12-float window read
//   from LDS (no shared-norm round trip, no extra LDS).
// R2 failure mode: 2-wave blocks + 128 barrier-drains/block -> VALUBusy 20%.

#define BB 8
#define CC 256
#define HH 96
#define WW 128
#define HW (HH*WW)
#define CHW (CC*HW)
#define NDISP 81
#define TXS 64          // tile width: 16 tx * 4 px
#define TYS 4           // tile rows: 4 ty * 1 row
#define HX4 18          // halo row width in float4 (72 floats = 64 + 8)
#define NSLOT (TYS*HX4) // 72 float4 slots per channel (4 halo rows)
#define CK 4            // channels per chunk
#define NCHK (CC/CK)    // 64 chunks
#define NST (NSLOT*CK)  // 288 float4 slots per chunk
#define NJ 5            // ceil(288/64) staging rounds
#define YT (HH/TYS)     // 24
#define XT 2
#define NTILES (BB*YT*XT) // 384
#define NGRP 9
#define EPSN 1e-12f

__global__ __launch_bounds__(64, 3) void corr_kernel(
    const float* __restrict__ fr, const float* __restrict__ fq,
    float* __restrict__ out)
{
    __shared__ float4 s_fq[NST];   // 4608 B, wave-private (1 wave/block)

    const int lane = threadIdx.x;
    const int tx   = lane & 15;    // 0..15, 4 px each
    const int ty   = lane >> 4;    // 0..3

    const int tile = blockIdx.x % NTILES;  // dy at stride 384 ≡ 0 mod 8 → same XCD
    const int dy   = blockIdx.x / NTILES;  // 0..8
    const int b    = tile / (YT * XT);
    const int rem  = tile % (YT * XT);
    const int y0   = (rem >> 1) * TYS;
    const int x0   = (rem & 1) * TXS;

    // ---- staging slot ownership: slot i = c*72 + row*18 + col4, i = 64j+lane ----
    int  iidx[NJ]; int soff[NJ]; bool sact[NJ]; bool sval[NJ];
#pragma unroll
    for (int j = 0; j < NJ; ++j) {
        int i = 64 * j + lane;
        iidx[j] = i;
        sact[j] = (i < NST);
        int c    = i / NSLOT;       // chunk-local channel 0..3
        int s    = i % NSLOT;
        int row  = s / HX4;         // halo row 0..3 == output row offset
        int col4 = s % HX4;
        int gy = y0 + dy - 4 + row;
        int gx = x0 - 4 + col4 * 4;
        sval[j] = sact[j] && ((unsigned)gy < (unsigned)HH) && ((unsigned)gx < (unsigned)WW);
        soff[j] = b * CHW + c * HW + gy * WW + gx;
    }

    // pre-zero OOB slots once (they are OOB for every chunk; never rewritten)
#pragma unroll
    for (int j = 0; j < NJ; ++j)
        if (sact[j] && !sval[j]) s_fq[iidx[j]] = make_float4(0.f, 0.f, 0.f, 0.f);

    // ---- prefetch chunk 0 ----
    float4 v[NJ];
#pragma unroll
    for (int j = 0; j < NJ; ++j)
        if (sval[j]) v[j] = *(const float4*)(fq + soff[j]);

    const int frbase = b * CHW + (y0 + ty) * WW + x0 + tx * 4;
    float4 fra[CK];
#pragma unroll
    for (int c = 0; c < CK; ++c)
        fra[c] = *(const float4*)(fr + frbase + c * HW);

    float4 acc[9];
#pragma unroll
    for (int d = 0; d < 9; ++d) acc[d] = make_float4(0.f, 0.f, 0.f, 0.f);
    float sqn[12];
#pragma unroll
    for (int i = 0; i < 12; ++i) sqn[i] = 0.f;
    float4 fr2 = make_float4(0.f, 0.f, 0.f, 0.f);

#pragma unroll 1
    for (int ch = 0; ch < NCHK; ++ch) {
        const int nch = (ch + 1 < NCHK) ? ch + 1 : ch;   // clamp: last iter reloads (dead)
        const int nco = nch * (CK * HW);

        // ---- stage current chunk to LDS, prefetch next into v ----
#pragma unroll
        for (int j = 0; j < NJ; ++j) {
            if (sval[j]) {
                s_fq[iidx[j]] = v[j];
                v[j] = *(const float4*)(fq + soff[j] + nco);
            }
        }

        // ---- compute 4 channels (reads wait on lgkmcnt only; no barrier) ----
#pragma unroll
        for (int c = 0; c < CK; ++c) {
            float4 a = fra[c];
            fra[c] = *(const float4*)(fr + frbase + nco + c * HW);  // roll fr
            fr2.x += a.x * a.x; fr2.y += a.y * a.y;
            fr2.z += a.z * a.z; fr2.w += a.w * a.w;

            float rw[12];
#pragma unroll
            for (int s4 = 0; s4 < 3; ++s4) {
                float4 t = s_fq[c * NSLOT + ty * HX4 + tx + s4];
                rw[s4 * 4 + 0] = t.x;
                rw[s4 * 4 + 1] = t.y;
                rw[s4 * 4 + 2] = t.z;
                rw[s4 * 4 + 3] = t.w;
            }
#pragma unroll
            for (int i = 0; i < 12; ++i) sqn[i] += rw[i] * rw[i];
#pragma unroll
            for (int dx = 0; dx < 9; ++dx) {
                acc[dx].x += a.x * rw[dx + 0];
                acc[dx].y += a.y * rw[dx + 1];
                acc[dx].z += a.z * rw[dx + 2];
                acc[dx].w += a.w * rw[dx + 3];
            }
        }
    }

    // ---- epilogue: all norms in registers ----
    float inq[12];
#pragma unroll
    for (int i = 0; i < 12; ++i)
        inq[i] = 1.0f / fmaxf(sqrtf(sqn[i]), EPSN);

    float4 ir;
    ir.x = 1.0f / fmaxf(sqrtf(fr2.x), EPSN);
    ir.y = 1.0f / fmaxf(sqrtf(fr2.y), EPSN);
    ir.z = 1.0f / fmaxf(sqrtf(fr2.z), EPSN);
    ir.w = 1.0f / fmaxf(sqrtf(fr2.w), EPSN);

    const float inv256 = 1.0f / 256.0f;
    const int obase = (b * NDISP + dy * 9) * HW + (y0 + ty) * WW + x0 + tx * 4;
#pragma unroll
    for (int dx = 0; dx < 9; ++dx) {
        float4 a = acc[dx];
        float4 o;
        o.x = a.x * ir.x * inq[dx + 0] * inv256;
        o.y = a.y * ir.y * inq[dx + 1] * inv256;
        o.z = a.z * ir.z * inq[dx + 2] * inv256;
        o.w = a.w * ir.w * inq[dx + 3] * inv256;
        *(float4*)(out + obase + dx * HW) = o;
    }
}

extern "C" void kernel_launch(void* const* d_in, const int* in_sizes, int n_in,
                              void* d_out, int out_size, void* d_ws, size_t ws_size,
                              hipStream_t stream) {
    const float* fr = (const float*)d_in[0];
    const float* fq = (const float*)d_in[1];
    float* out = (float*)d_out;
    corr_kernel<<<dim3(NTILES * NGRP), dim3(64), 0, stream>>>(fr, fq, out);
}

// Round 4
// 376.275 us; speedup vs baseline: 1.9103x; 1.9103x over previous
//
#include <hip/hip_runtime.h>

// Correlation layer: out[b, dy*9+dx, y, x] =
//   (1/256) * sum_c frn[b,c,y,x] * fqn_pad[b,c,y+dy,x+dx]   (pad r=4)
// Identity: dot(frn,fqn) = dot(fr,fq) * invnorm(fr) * invnorm(fq).
//
// R4: R3's barrier-free 1-wave blocks, register pressure fixed.
// R3 failure: ~115 VGPR demand vs 64 allotted ((64,3) => 64-reg cap on this
// toolchain) -> K-loop scratch spill -> 897MB HBM writes, VALUBusy 9%.
// Changes: drop register prefetch (v[]) and fr roll (fra[]); stage with
// short-lived load->ds_write (same-wave LDS ordering, no __syncthreads);
// __launch_bounds__(64,2) -> 128-reg cap (observed (64,2)->128 on R1).
// Steady-state ~70 regs, peak ~105 -> no spill.

#define BB 8
#define CC 256
#define HH 96
#define WW 128
#define HW (HH*WW)
#define CHW (CC*HW)
#define NDISP 81
#define TXS 64          // tile width: 16 tx * 4 px
#define TYS 4           // tile rows
#define HX4 18          // halo row width in float4 (72 floats = 64 + 8)
#define NSLOT (TYS*HX4) // 72 float4 slots per channel
#define CK 4            // channels per chunk
#define NCHK (CC/CK)    // 64 chunks
#define NST (NSLOT*CK)  // 288 float4 slots per chunk
#define NJ 5            // ceil(288/64) staging rounds
#define YT (HH/TYS)     // 24
#define XT 2
#define NTILES (BB*YT*XT) // 384
#define NGRP 9
#define EPSN 1e-12f

__global__ __launch_bounds__(64, 2) void corr_kernel(
    const float* __restrict__ fr, const float* __restrict__ fq,
    float* __restrict__ out)
{
    __shared__ float4 s_fq[NST];   // 4608 B, wave-private (1 wave/block)

    const int lane = threadIdx.x;
    const int tx   = lane & 15;    // 0..15, 4 px each
    const int ty   = lane >> 4;    // 0..3

    const int tile = blockIdx.x % NTILES;  // 9 dy-copies of a tile: stride 384 ≡ 0 mod 8 → same XCD
    const int dy   = blockIdx.x / NTILES;  // 0..8
    const int b    = tile / (YT * XT);
    const int rem  = tile % (YT * XT);
    const int y0   = (rem >> 1) * TYS;
    const int x0   = (rem & 1) * TXS;

    // ---- staging slot ownership: slot i = c*72 + row*18 + col4, i = 64j+lane ----
    int soff[NJ]; bool sval[NJ];
#pragma unroll
    for (int j = 0; j < NJ; ++j) {
        int i = 64 * j + lane;
        bool act = (i < NST);
        int c    = i / NSLOT;       // chunk-local channel 0..3
        int s    = i % NSLOT;
        int row  = s / HX4;         // halo row == output row offset
        int col4 = s % HX4;
        int gy = y0 + dy - 4 + row;
        int gx = x0 - 4 + col4 * 4;
        sval[j] = act && ((unsigned)gy < (unsigned)HH) && ((unsigned)gx < (unsigned)WW);
        soff[j] = b * CHW + c * HW + gy * WW + gx;
        // pre-zero OOB slots once; they are OOB for every chunk, never rewritten
        if (act && !sval[j]) s_fq[i] = make_float4(0.f, 0.f, 0.f, 0.f);
    }

    const int frbase = b * CHW + (y0 + ty) * WW + x0 + tx * 4;

    float4 acc[9];
#pragma unroll
    for (int d = 0; d < 9; ++d) acc[d] = make_float4(0.f, 0.f, 0.f, 0.f);
    float sqn[12];
#pragma unroll
    for (int i = 0; i < 12; ++i) sqn[i] = 0.f;
    float4 fr2 = make_float4(0.f, 0.f, 0.f, 0.f);

#pragma unroll 1
    for (int ch = 0; ch < NCHK; ++ch) {
        const int co = ch * (CK * HW);

        // ---- stage chunk into LDS (short-lived regs; same-wave ordering,
        //      no barrier: ds_write waits vmcnt, ds_read waits lgkmcnt) ----
#pragma unroll
        for (int j = 0; j < NJ; ++j) {
            if (sval[j]) {
                float4 t = *(const float4*)(fq + soff[j] + co);
                s_fq[64 * j + lane] = t;
            }
        }

        // ---- compute 4 channels ----
#pragma unroll
        for (int c = 0; c < CK; ++c) {
            float4 a = *(const float4*)(fr + frbase + co + c * HW);
            fr2.x += a.x * a.x; fr2.y += a.y * a.y;
            fr2.z += a.z * a.z; fr2.w += a.w * a.w;

            float rw[12];
#pragma unroll
            for (int s4 = 0; s4 < 3; ++s4) {
                float4 t = s_fq[c * NSLOT + ty * HX4 + tx + s4];
                rw[s4 * 4 + 0] = t.x;
                rw[s4 * 4 + 1] = t.y;
                rw[s4 * 4 + 2] = t.z;
                rw[s4 * 4 + 3] = t.w;
            }
#pragma unroll
            for (int i = 0; i < 12; ++i) sqn[i] += rw[i] * rw[i];
#pragma unroll
            for (int dx = 0; dx < 9; ++dx) {
                acc[dx].x += a.x * rw[dx + 0];
                acc[dx].y += a.y * rw[dx + 1];
                acc[dx].z += a.z * rw[dx + 2];
                acc[dx].w += a.w * rw[dx + 3];
            }
        }
    }

    // ---- epilogue: all norms in registers ----
    float inq[12];
#pragma unroll
    for (int i = 0; i < 12; ++i)
        inq[i] = 1.0f / fmaxf(sqrtf(sqn[i]), EPSN);

    float4 ir;
    ir.x = 1.0f / fmaxf(sqrtf(fr2.x), EPSN);
    ir.y = 1.0f / fmaxf(sqrtf(fr2.y), EPSN);
    ir.z = 1.0f / fmaxf(sqrtf(fr2.z), EPSN);
    ir.w = 1.0f / fmaxf(sqrtf(fr2.w), EPSN);

    const float inv256 = 1.0f / 256.0f;
    const int obase = (b * NDISP + dy * 9) * HW + (y0 + ty) * WW + x0 + tx * 4;
#pragma unroll
    for (int dx = 0; dx < 9; ++dx) {
        float4 a = acc[dx];
        float4 o;
        o.x = a.x * ir.x * inq[dx + 0] * inv256;
        o.y = a.y * ir.y * inq[dx + 1] * inv256;
        o.z = a.z * ir.z * inq[dx + 2] * inv256;
        o.w = a.w * ir.w * inq[dx + 3] * inv256;
        *(float4*)(out + obase + dx * HW) = o;
    }
}

extern "C" void kernel_launch(void* const* d_in, const int* in_sizes, int n_in,
                              void* d_out, int out_size, void* d_ws, size_t ws_size,
                              hipStream_t stream) {
    const float* fr = (const float*)d_in[0];
    const float* fq = (const float*)d_in[1];
    float* out = (float*)d_out;
    corr_kernel<<<dim3(NTILES * NGRP), dim3(64), 0, stream>>>(fr, fq, out);
}